// Round 7
// baseline (603.773 us; speedup 1.0000x reference)
//
#include <hip/hip_runtime.h>

// PerceptronSP: 8000 independent per-pixel MLPs sharing input x.
//   h1 = leaky(x @ W1[p] + b1[p])   [32x25]@[25x128]
//   h2 = leaky(h1 @ W2[p] + b2[p])  [32x128]@[128x128]
//   y[:,p] = h2 @ W3[p] + b3[p]
// ~640 MB of weights streamed once -> ~100 us floor @ 6.6 TB/s.
//
// Round 7: stream W2 via __builtin_amdgcn_global_load_lds (width 16) into a
// 2x4KB LDS double buffer, counted vmcnt(4) waits (never 0 in loop), single
// wave per block -> NO barriers, no forced vmcnt(0) drains. Register-dest
// loads + drains capped us at 3.3 TB/s (R3/R6); register dbuf spills (R4/R5).
//
// lane = bg*16+kg: rows 8bg..8bg+7  x  cols {4kg..+3} u {64+4kg..+3}.

constexpr int DIM_IN = 25;
constexpr int H      = 128;
constexpr int P      = 8000;
constexpr int BS     = 32;
constexpr float NEG  = 0.01f;

__device__ __forceinline__ float leaky(float v) { return v >= 0.f ? v : NEG * v; }

// pack two f32 into bf16x2 (round-to-nearest-even)
__device__ __forceinline__ unsigned pkbf2(float a, float b) {
    unsigned ua = __builtin_bit_cast(unsigned, a);
    unsigned ub = __builtin_bit_cast(unsigned, b);
    ua = (ua + 0x7fffu + ((ua >> 16) & 1u)) >> 16;
    ub = (ub + 0x7fffu + ((ub >> 16) & 1u)) >> 16;
    return ua | (ub << 16);
}
__device__ __forceinline__ float lo16(unsigned u) { return __builtin_bit_cast(float, u << 16); }
__device__ __forceinline__ float hi16(unsigned u) { return __builtin_bit_cast(float, u & 0xffff0000u); }

// stage one 4KB W2 tile (8 rows x 128 cols f32) into LDS: 4 x 1KB insts.
// global src is per-lane (base + lane*16B); LDS dst is wave-uniform base
// (HW adds lane*16B) -- m104/m108 semantics.
#define STAGE_TILE(DSTBASE, ROWBASE) {                                         \
    const float* gsrc_ = W2p + (size_t)(ROWBASE) * H + (t << 2);               \
    _Pragma("unroll")                                                          \
    for (int q_ = 0; q_ < 4; ++q_)                                             \
        __builtin_amdgcn_global_load_lds(                                      \
            (const __attribute__((address_space(1))) unsigned*)(gsrc_ + q_ * 256), \
            (__attribute__((address_space(3))) unsigned*)((DSTBASE) + q_ * 256),   \
            16, 0, 0); }

// consume one 8-row tile from LDS: acc2 += h1[r0..r0+7][k] * W2tile[k][cols]
// KP = bf16-pair base index (= 4 * tile_index)
#define TILE_FMA(TB, KP) {                                                     \
    _Pragma("unroll")                                                          \
    for (int half_ = 0; half_ < 2; ++half_) {                                  \
        float av_[8][4];                                                       \
        _Pragma("unroll")                                                      \
        for (int i_ = 0; i_ < 8; ++i_) {                                       \
            const uint2 u_ = *reinterpret_cast<const uint2*>(                  \
                &h1u[r0 + i_][((KP) + half_ * 2) ^ sw2]);                      \
            av_[i_][0] = lo16(u_.x); av_[i_][1] = hi16(u_.x);                  \
            av_[i_][2] = lo16(u_.y); av_[i_][3] = hi16(u_.y);                  \
        }                                                                      \
        _Pragma("unroll")                                                      \
        for (int k_ = 0; k_ < 4; ++k_) {                                       \
            const float4 wl_ = *reinterpret_cast<const float4*>(               \
                (TB) + (half_ * 4 + k_) * H + c0);                             \
            const float4 wh_ = *reinterpret_cast<const float4*>(               \
                (TB) + (half_ * 4 + k_) * H + 64 + c0);                        \
            const float wv_[8] = {wl_.x, wl_.y, wl_.z, wl_.w,                  \
                                  wh_.x, wh_.y, wh_.z, wh_.w};                 \
            _Pragma("unroll")                                                  \
            for (int i_ = 0; i_ < 8; ++i_)                                     \
                _Pragma("unroll")                                              \
                for (int c_ = 0; c_ < 8; ++c_)                                 \
                    acc2[i_][c_] += av_[i_][k_] * wv_[c_];                     \
        }                                                                      \
    } }

__global__ __launch_bounds__(64, 2) void pixel_mlp_kernel(
    const float* __restrict__ x,    // [BS][DIM_IN]
    const float* __restrict__ W1,   // [P][DIM_IN][H]
    const float* __restrict__ b1,   // [P][H]
    const float* __restrict__ W2,   // [P][H][H]
    const float* __restrict__ b2,   // [P][H]
    const float* __restrict__ W3,   // [P][H]
    const float* __restrict__ b3,   // [P]
    float* __restrict__ y)          // [BS][P]
{
    const int p   = blockIdx.x;
    const int t   = threadIdx.x;    // 0..63, one wave
    const int kg  = t & 15;
    const int bg  = t >> 4;
    const int c0  = kg << 2;
    const int r0  = bg << 3;
    const int sw2 = bg << 1;        // XOR swizzle on bf16-pair index

    __shared__ float    sxT[DIM_IN][BS];  // 3.2 KB
    __shared__ unsigned h1u[BS][H / 2];   // 8 KB, h1 as bf16 pairs
    __shared__ float    w2t[2][8 * H];    // 8 KB, W2 tile double buffer

    const float* W1p = W1 + (size_t)p * (DIM_IN * H);
    const float* W2p = W2 + (size_t)p * (H * H);

    // biases / W3 hoisted (issued before staging -> retire earliest, in-order)
    const float4 b1l = *reinterpret_cast<const float4*>(b1 + (size_t)p * H + c0);
    const float4 b1h = *reinterpret_cast<const float4*>(b1 + (size_t)p * H + 64 + c0);
    const float4 b2l = *reinterpret_cast<const float4*>(b2 + (size_t)p * H + c0);
    const float4 b2h = *reinterpret_cast<const float4*>(b2 + (size_t)p * H + 64 + c0);
    const float4 w3l = *reinterpret_cast<const float4*>(W3 + (size_t)p * H + c0);
    const float4 w3h = *reinterpret_cast<const float4*>(W3 + (size_t)p * H + 64 + c0);

    // W2 tiles 0 and 1 in flight during all of layer 1
    STAGE_TILE(&w2t[0][0], 0)
    STAGE_TILE(&w2t[1][0], 8)

    // stage x^T (single-wave block: LDS pipe is in-order, no barrier needed)
    for (int i = t; i < DIM_IN * BS; i += 64) {
        sxT[i >> 5][i & 31] = x[(i & 31) * DIM_IN + (i >> 5)];
    }
    asm volatile("s_waitcnt lgkmcnt(0)" ::: "memory");

    // ---------------- layer 1: h1 = leaky(x @ W1 + b1) ----------------
    float acc1[8][8];
    {
        const float bv[8] = {b1l.x, b1l.y, b1l.z, b1l.w, b1h.x, b1h.y, b1h.z, b1h.w};
        #pragma unroll
        for (int i = 0; i < 8; ++i)
            #pragma unroll
            for (int c = 0; c < 8; ++c)
                acc1[i][c] = bv[c];
    }
    #pragma unroll 5
    for (int d = 0; d < DIM_IN; ++d) {
        const float4 a0 = *reinterpret_cast<const float4*>(&sxT[d][r0]);
        const float4 a1 = *reinterpret_cast<const float4*>(&sxT[d][r0 + 4]);
        const float av[8] = {a0.x, a0.y, a0.z, a0.w, a1.x, a1.y, a1.z, a1.w};
        const float4 wl = *reinterpret_cast<const float4*>(W1p + d * H + c0);
        const float4 wh = *reinterpret_cast<const float4*>(W1p + d * H + 64 + c0);
        const float wv[8] = {wl.x, wl.y, wl.z, wl.w, wh.x, wh.y, wh.z, wh.w};
        #pragma unroll
        for (int i = 0; i < 8; ++i)
            #pragma unroll
            for (int c = 0; c < 8; ++c)
                acc1[i][c] += av[i] * wv[c];
    }

    // write h1 (leaky) as bf16 pairs, pair-index XOR-swizzled by row stripe
    #pragma unroll
    for (int i = 0; i < 8; ++i) {
        uint2 lo, hi;
        lo.x = pkbf2(leaky(acc1[i][0]), leaky(acc1[i][1]));
        lo.y = pkbf2(leaky(acc1[i][2]), leaky(acc1[i][3]));
        hi.x = pkbf2(leaky(acc1[i][4]), leaky(acc1[i][5]));
        hi.y = pkbf2(leaky(acc1[i][6]), leaky(acc1[i][7]));
        *reinterpret_cast<uint2*>(&h1u[r0 + i][( 2 * kg     ) ^ sw2]) = lo;
        *reinterpret_cast<uint2*>(&h1u[r0 + i][(32 + 2 * kg ) ^ sw2]) = hi;
    }
    asm volatile("s_waitcnt lgkmcnt(0)" ::: "memory");

    // ---------------- layer 2: h2 = leaky(h1 @ W2 + b2) ----------------
    float acc2[8][8];
    {
        const float bv[8] = {b2l.x, b2l.y, b2l.z, b2l.w, b2h.x, b2h.y, b2h.z, b2h.w};
        #pragma unroll
        for (int i = 0; i < 8; ++i)
            #pragma unroll
            for (int c = 0; c < 8; ++c)
                acc2[i][c] = bv[c];
    }

    // 16 tiles of 8 k-rows; prefetch distance 1; vmcnt never drained in loop.
    // outstanding at loop top: T_t (4) + T_{t+1} (4) = 8 -> vmcnt(4) = T_t ready.
    #pragma unroll 1
    for (int tt = 0; tt < 14; ++tt) {
        asm volatile("s_waitcnt vmcnt(4)" ::: "memory");
        const float* tb = &w2t[tt & 1][0];
        TILE_FMA(tb, tt * 4)
        asm volatile("" ::: "memory");   // reads of buf done before restage
        STAGE_TILE(&w2t[tt & 1][0], (tt + 2) * 8)
    }
    asm volatile("s_waitcnt vmcnt(4)" ::: "memory");
    TILE_FMA(&w2t[0][0], 56)
    asm volatile("s_waitcnt vmcnt(0)" ::: "memory");
    TILE_FMA(&w2t[1][0], 60)

    // ---------------- layer 3: y = leaky(h2) @ W3 + b3 ----------------
    const float w3v[8] = {w3l.x, w3l.y, w3l.z, w3l.w, w3h.x, w3h.y, w3h.z, w3h.w};
    float part[8];
    #pragma unroll
    for (int i = 0; i < 8; ++i) {
        float s = 0.f;
        #pragma unroll
        for (int c = 0; c < 8; ++c)
            s += leaky(acc2[i][c]) * w3v[c];
        part[i] = s;
    }
    #pragma unroll
    for (int m = 8; m >= 1; m >>= 1) {
        #pragma unroll
        for (int i = 0; i < 8; ++i)
            part[i] += __shfl_xor(part[i], m);
    }
    if (kg == 0) {
        const float bias = b3[p];
        #pragma unroll
        for (int i = 0; i < 8; ++i)
            y[(size_t)(r0 + i) * P + p] = part[i] + bias;
    }
}

extern "C" void kernel_launch(void* const* d_in, const int* in_sizes, int n_in,
                              void* d_out, int out_size, void* d_ws, size_t ws_size,
                              hipStream_t stream) {
    const float* x  = (const float*)d_in[0];
    const float* W1 = (const float*)d_in[1];
    const float* b1 = (const float*)d_in[2];
    const float* W2 = (const float*)d_in[3];
    const float* b2 = (const float*)d_in[4];
    const float* W3 = (const float*)d_in[5];
    const float* b3 = (const float*)d_in[6];
    float* y = (float*)d_out;

    pixel_mlp_kernel<<<dim3(P), dim3(64), 0, stream>>>(x, W1, b1, W2, b2, W3, b3, y);
}

// Round 8
// 161.894 us; speedup vs baseline: 3.7294x; 3.7294x over previous
//
#include <hip/hip_runtime.h>

// PerceptronSP: 8000 independent per-pixel MLPs sharing input x.
//   h1 = leaky(x @ W1[p] + b1[p])   [32x25]@[25x128]   f32 VALU
//   h2 = leaky(h1 @ W2[p] + b2[p])  [32x128]@[128x128] bf16 MFMA (this round)
//   y[:,p] = h2 @ W3[p] + b3[p]
// ~650 MB streamed once -> ~100 us floor @ 6.6 TB/s. f32-VALU layer 2 was
// co-compute-bound (~8200 VALU insts/pixel ~ 65us CU-issue) -> MFMA offload.
//
// W2 staged via global_load_lds (pattern correctness-verified in R7) in
// 32x128 f32 tiles, 2-deep double buffer, counted vmcnt(16) waits.
// MFMA mfma_f32_16x16x32_bf16: A row = lane&15, k = 8*(lane>>4)+j (same slot
// mapping used for B -> any hw K-permutation cancels); D col = lane&15,
// row = 4*(lane>>4)+reg (guide-verified m89/m91).

constexpr int DIM_IN = 25;
constexpr int H      = 128;
constexpr int P      = 8000;
constexpr int BS     = 32;
constexpr float NEG  = 0.01f;

typedef short  short4v __attribute__((ext_vector_type(4)));
typedef short  short8v __attribute__((ext_vector_type(8)));
typedef float  f32x4   __attribute__((ext_vector_type(4)));

__device__ __forceinline__ float leaky(float v) { return v >= 0.f ? v : NEG * v; }

__device__ __forceinline__ short bf_rne(float f) {   // f32 -> bf16 bits, RNE
    unsigned u = __builtin_bit_cast(unsigned, f);
    return (short)((u + 0x7fffu + ((u >> 16) & 1u)) >> 16);
}
__device__ __forceinline__ short bf_rna(float f) {   // f32 -> bf16 bits, nearest
    unsigned u = __builtin_bit_cast(unsigned, f);
    return (short)((u + 0x8000u) >> 16);
}

// stage one 16KB W2 tile (32 rows x 128 f32) into LDS: 16 x 1KB DMA insts.
// global src per-lane (base + t*16B); LDS dst wave-uniform (HW adds lane*16B).
#define STAGE_TILE(BUF, KT) {                                                  \
    const float* gsrc_ = W2p + (size_t)(KT) * (32 * H) + (t << 2);             \
    float* dst_ = &w2t[BUF][0];                                                \
    _Pragma("unroll")                                                          \
    for (int q_ = 0; q_ < 16; ++q_)                                            \
        __builtin_amdgcn_global_load_lds(                                      \
            (const __attribute__((address_space(1))) unsigned*)(gsrc_ + q_ * 256), \
            (__attribute__((address_space(3))) unsigned*)(dst_ + q_ * 256),    \
            16, 0, 0); }

// consume one 32-k-row tile: 2 A-frags (one b128 LDS read each), 8 col-blocks
// x {8 ds_read_b32 + bf16 round -> B-frag, 2 MFMA}.
#define CONSUME_TILE(BUF, KB) {                                                \
    const short8v a0_ = *reinterpret_cast<const short8v*>(                     \
        &h1b[cc][32 * (KB) + 8 * gg]);                                         \
    const short8v a1_ = *reinterpret_cast<const short8v*>(                     \
        &h1b[16 + cc][32 * (KB) + 8 * gg]);                                    \
    const float* tb_ = &w2t[BUF][8 * gg * H + cc];                             \
    _Pragma("unroll")                                                          \
    for (int nb_ = 0; nb_ < 8; ++nb_) {                                        \
        const float* col_ = tb_ + 16 * nb_;                                    \
        short8v bf_;                                                           \
        bf_[0] = bf_rna(col_[0 * H]); bf_[1] = bf_rna(col_[1 * H]);            \
        bf_[2] = bf_rna(col_[2 * H]); bf_[3] = bf_rna(col_[3 * H]);            \
        bf_[4] = bf_rna(col_[4 * H]); bf_[5] = bf_rna(col_[5 * H]);            \
        bf_[6] = bf_rna(col_[6 * H]); bf_[7] = bf_rna(col_[7 * H]);            \
        ac0[nb_] = __builtin_amdgcn_mfma_f32_16x16x32_bf16(a0_, bf_, ac0[nb_], 0, 0, 0); \
        ac1[nb_] = __builtin_amdgcn_mfma_f32_16x16x32_bf16(a1_, bf_, ac1[nb_], 0, 0, 0); \
    } }

__global__ __launch_bounds__(64, 1) void pixel_mlp_kernel(
    const float* __restrict__ x,    // [BS][DIM_IN]
    const float* __restrict__ W1,   // [P][DIM_IN][H]
    const float* __restrict__ b1,   // [P][H]
    const float* __restrict__ W2,   // [P][H][H]
    const float* __restrict__ b2,   // [P][H]
    const float* __restrict__ W3,   // [P][H]
    const float* __restrict__ b3,   // [P]
    float* __restrict__ y)          // [BS][P]
{
    const int p  = blockIdx.x;
    const int t  = threadIdx.x;     // 0..63, one wave
    const int cc = t & 15;          // MFMA col lane / layer-1 col group
    const int gg = t >> 4;          // MFMA k/row group / layer-1 row group
    const int c0 = cc << 2;         // layer-1: first col of low half
    const int r0 = gg << 3;         // layer-1: first row

    __shared__ float sxT[DIM_IN][BS];   // 3.2 KB
    __shared__ short h1b[BS][H];        // 8 KB, h1 as bf16 bits, LINEAR layout
    __shared__ float w2t[2][32 * H];    // 32 KB, W2 tile double buffer

    const float* W1p = W1 + (size_t)p * (DIM_IN * H);
    const float* W2p = W2 + (size_t)p * (H * H);

    // ---- small loads first (oldest in vmcnt FIFO; retire before staging) ----
    const float4 b1l = *reinterpret_cast<const float4*>(b1 + (size_t)p * H + c0);
    const float4 b1h = *reinterpret_cast<const float4*>(b1 + (size_t)p * H + 64 + c0);
    float b2v[8], w3v[8];
    #pragma unroll
    for (int nb = 0; nb < 8; ++nb) {
        b2v[nb] = b2[(size_t)p * H + 16 * nb + cc];
        w3v[nb] = W3[(size_t)p * H + 16 * nb + cc];
    }
    const float b3s = b3[p];
    asm volatile("" ::: "memory");

    // W2 tiles 0,1 in flight during all of layer 1
    STAGE_TILE(0, 0)
    STAGE_TILE(1, 1)
    asm volatile("" ::: "memory");

    // stage x^T
    for (int i = t; i < DIM_IN * BS; i += 64)
        sxT[i >> 5][i & 31] = x[(i & 31) * DIM_IN + (i >> 5)];
    asm volatile("s_waitcnt lgkmcnt(0)" ::: "memory");

    // ---------------- layer 1: h1 = leaky(x @ W1 + b1), f32 VALU ----------------
    float aL1[8][8];
    {
        const float bv[8] = {b1l.x, b1l.y, b1l.z, b1l.w, b1h.x, b1h.y, b1h.z, b1h.w};
        #pragma unroll
        for (int i = 0; i < 8; ++i)
            #pragma unroll
            for (int c = 0; c < 8; ++c)
                aL1[i][c] = bv[c];
    }
    #pragma unroll 5
    for (int d = 0; d < DIM_IN; ++d) {
        const float4 a0 = *reinterpret_cast<const float4*>(&sxT[d][r0]);
        const float4 a1 = *reinterpret_cast<const float4*>(&sxT[d][r0 + 4]);
        const float av[8] = {a0.x, a0.y, a0.z, a0.w, a1.x, a1.y, a1.z, a1.w};
        const float4 wl = *reinterpret_cast<const float4*>(W1p + d * H + c0);
        const float4 wh = *reinterpret_cast<const float4*>(W1p + d * H + 64 + c0);
        const float wv[8] = {wl.x, wl.y, wl.z, wl.w, wh.x, wh.y, wh.z, wh.w};
        #pragma unroll
        for (int i = 0; i < 8; ++i)
            #pragma unroll
            for (int c = 0; c < 8; ++c)
                aL1[i][c] += av[i] * wv[c];
    }

    // write h1 (leaky, RNE bf16) into the linear [32][128] layout
    #pragma unroll
    for (int i = 0; i < 8; ++i) {
        short4v lo, hi;
        lo[0] = bf_rne(leaky(aL1[i][0])); lo[1] = bf_rne(leaky(aL1[i][1]));
        lo[2] = bf_rne(leaky(aL1[i][2])); lo[3] = bf_rne(leaky(aL1[i][3]));
        hi[0] = bf_rne(leaky(aL1[i][4])); hi[1] = bf_rne(leaky(aL1[i][5]));
        hi[2] = bf_rne(leaky(aL1[i][6])); hi[3] = bf_rne(leaky(aL1[i][7]));
        *reinterpret_cast<short4v*>(&h1b[r0 + i][4 * cc])      = lo;
        *reinterpret_cast<short4v*>(&h1b[r0 + i][64 + 4 * cc]) = hi;
    }
    asm volatile("s_waitcnt lgkmcnt(0)" ::: "memory");
    __builtin_amdgcn_sched_barrier(0);

    // ---------------- layer 2: h2 = leaky(h1 @ W2 + b2), bf16 MFMA ----------------
    f32x4 ac0[8], ac1[8];
    #pragma unroll
    for (int nb = 0; nb < 8; ++nb) {
        ac0[nb] = (f32x4){0.f, 0.f, 0.f, 0.f};
        ac1[nb] = (f32x4){0.f, 0.f, 0.f, 0.f};
    }

    // 4 tiles, prefetch depth 2; vmcnt(16) = oldest tile fully landed.
    asm volatile("s_waitcnt vmcnt(16)" ::: "memory");
    CONSUME_TILE(0, 0)
    asm volatile("s_waitcnt lgkmcnt(0)" ::: "memory");
    STAGE_TILE(0, 2)
    asm volatile("s_waitcnt vmcnt(16)" ::: "memory");
    CONSUME_TILE(1, 1)
    asm volatile("s_waitcnt lgkmcnt(0)" ::: "memory");
    STAGE_TILE(1, 3)
    asm volatile("s_waitcnt vmcnt(16)" ::: "memory");
    CONSUME_TILE(0, 2)
    asm volatile("s_waitcnt vmcnt(0)" ::: "memory");
    CONSUME_TILE(1, 3)

    // ---------------- layer 3: y = leaky(h2 + b2) @ W3 + b3 ----------------
    // lane holds D rows b = 16*mb + 4*gg + q, col n = 16*nb + cc
    float s0[4], s1[4];
    #pragma unroll
    for (int q = 0; q < 4; ++q) {
        float a = 0.f, b = 0.f;
        #pragma unroll
        for (int nb = 0; nb < 8; ++nb) {
            a += leaky(ac0[nb][q] + b2v[nb]) * w3v[nb];
            b += leaky(ac1[nb][q] + b2v[nb]) * w3v[nb];
        }
        s0[q] = a; s1[q] = b;
    }
    // reduce across the 16 cc lanes
    #pragma unroll
    for (int m = 8; m >= 1; m >>= 1) {
        #pragma unroll
        for (int q = 0; q < 4; ++q) {
            s0[q] += __shfl_xor(s0[q], m);
            s1[q] += __shfl_xor(s1[q], m);
        }
    }
    if (cc == 0) {
        #pragma unroll
        for (int q = 0; q < 4; ++q) {
            y[(size_t)(4 * gg + q) * P + p]      = s0[q] + b3s;
            y[(size_t)(16 + 4 * gg + q) * P + p] = s1[q] + b3s;
        }
    }
}

extern "C" void kernel_launch(void* const* d_in, const int* in_sizes, int n_in,
                              void* d_out, int out_size, void* d_ws, size_t ws_size,
                              hipStream_t stream) {
    const float* x  = (const float*)d_in[0];
    const float* W1 = (const float*)d_in[1];
    const float* b1 = (const float*)d_in[2];
    const float* W2 = (const float*)d_in[3];
    const float* b2 = (const float*)d_in[4];
    const float* W3 = (const float*)d_in[5];
    const float* b3 = (const float*)d_in[6];
    float* y = (float*)d_out;

    pixel_mlp_kernel<<<dim3(P), dim3(64), 0, stream>>>(x, W1, b1, W2, b2, W3, b3, y);
}

// Round 12
// 137.345 us; speedup vs baseline: 4.3960x; 1.1787x over previous
//
#include <hip/hip_runtime.h>

// PerceptronSP: 8000 independent per-pixel MLPs sharing input x.
//   h1 = leaky(x @ W1[p] + b1[p])   [32x25]@[25x128]   f32 VALU
//   h2 = leaky(h1 @ W2[p] + b2[p])  [32x128]@[128x128] bf16 MFMA
//   y[:,p] = h2 @ W3[p] + b3[p]
// ~650 MB streamed once -> ~100 us floor @ 6.6 TB/s.
//
// R12: occupancy 3 -> 5 blocks/CU with the R8-VERIFIED K=32 intrinsic only.
// W2 tiles split by COLUMNS: 32 k-rows x 64 n-cols = 8 KB per tile; one K=32
// MFMA step consumes two half-tiles (nb 0-3 / nb 4-7). Loop unrolled x2 so
// the half index is a literal (no runtime-indexed accumulators, rule #20).
// LDS 27.2 KB total. Steady pipeline: vmcnt(8) -> consume -> lgkmcnt(0) ->
// restage (16 insts outstanding). Staging pattern verified R7/R8.

constexpr int DIM_IN = 25;
constexpr int H      = 128;
constexpr int P      = 8000;
constexpr int BS     = 32;
constexpr float NEG  = 0.01f;

typedef short  short4v __attribute__((ext_vector_type(4)));
typedef short  short8v __attribute__((ext_vector_type(8)));
typedef float  f32x4   __attribute__((ext_vector_type(4)));

__device__ __forceinline__ float leaky(float v) { return v >= 0.f ? v : NEG * v; }

__device__ __forceinline__ short bf_rne(float f) {   // f32 -> bf16 bits, RNE
    unsigned u = __builtin_bit_cast(unsigned, f);
    return (short)((u + 0x7fffu + ((u >> 16) & 1u)) >> 16);
}
__device__ __forceinline__ short bf_rna(float f) {   // f32 -> bf16 bits, round-nearest-away
    unsigned u = __builtin_bit_cast(unsigned, f);
    return (short)((u + 0x8000u) >> 16);
}

// stage one 8KB half-tile: W2 rows [32*KT, 32*KT+32) x cols [64*HF, 64*HF+64)
// 8 x 1KB DMA insts; inst q covers rows 4q..4q+3 (4 x 256B segments).
// LDS dst wave-uniform (HW adds lane*16B) -> buf is [32][64] f32 row-major.
#define STAGE_TILE(BUF, KT, HF) {                                              \
    const float* gsrc_ = W2p + (size_t)(KT) * (32 * H) + (HF) * 64             \
                         + (t >> 4) * H + ((t & 15) << 2);                     \
    float* dst_ = &w2t[BUF][0];                                                \
    _Pragma("unroll")                                                          \
    for (int q_ = 0; q_ < 8; ++q_)                                             \
        __builtin_amdgcn_global_load_lds(                                      \
            (const __attribute__((address_space(1))) unsigned*)(gsrc_ + q_ * 4 * H), \
            (__attribute__((address_space(3))) unsigned*)(dst_ + q_ * 256),    \
            16, 0, 0); }

// consume one half-tile with K=32 MFMA (R8-verified mapping: lane gg owns
// k = 8*gg + j for BOTH A and B -> any hw K-permutation cancels).
// A-frag: h1b[row=cc][k=32*KT+8*gg+j], one b128 read (+ row 16+cc).
// B-frag: buf[k=8*gg+j][n=16*nb+cc], 8 strided b32 reads + bf16 round.
// HF must be a LITERAL so accumulator indices are compile-time.
#define CONSUME_TILE(BUF, KT, HF) {                                            \
    const short8v a0_ = *reinterpret_cast<const short8v*>(                     \
        &h1b[cc][32 * (KT) + 8 * gg]);                                         \
    const short8v a1_ = *reinterpret_cast<const short8v*>(                     \
        &h1b[16 + cc][32 * (KT) + 8 * gg]);                                    \
    const float* tb_ = &w2t[BUF][8 * gg * 64 + cc];                            \
    _Pragma("unroll")                                                          \
    for (int nb_ = 0; nb_ < 4; ++nb_) {                                        \
        const float* col_ = tb_ + 16 * nb_;                                    \
        short8v bf_;                                                           \
        bf_[0] = bf_rna(col_[0 * 64]); bf_[1] = bf_rna(col_[1 * 64]);          \
        bf_[2] = bf_rna(col_[2 * 64]); bf_[3] = bf_rna(col_[3 * 64]);          \
        bf_[4] = bf_rna(col_[4 * 64]); bf_[5] = bf_rna(col_[5 * 64]);          \
        bf_[6] = bf_rna(col_[6 * 64]); bf_[7] = bf_rna(col_[7 * 64]);          \
        ac0[4 * (HF) + nb_] = __builtin_amdgcn_mfma_f32_16x16x32_bf16(         \
            a0_, bf_, ac0[4 * (HF) + nb_], 0, 0, 0);                           \
        ac1[4 * (HF) + nb_] = __builtin_amdgcn_mfma_f32_16x16x32_bf16(         \
            a1_, bf_, ac1[4 * (HF) + nb_], 0, 0, 0);                           \
    } }

__global__ __launch_bounds__(64, 2) void pixel_mlp_kernel(
    const float* __restrict__ x,    // [BS][DIM_IN]
    const float* __restrict__ W1,   // [P][DIM_IN][H]
    const float* __restrict__ b1,   // [P][H]
    const float* __restrict__ W2,   // [P][H][H]
    const float* __restrict__ b2,   // [P][H]
    const float* __restrict__ W3,   // [P][H]
    const float* __restrict__ b3,   // [P]
    float* __restrict__ y)          // [BS][P]
{
    const int p  = blockIdx.x;
    const int t  = threadIdx.x;     // 0..63, one wave
    const int cc = t & 15;          // MFMA n-lane / layer-1 col group
    const int gg = t >> 4;          // MFMA k-group / layer-1 row group
    const int c0 = cc << 2;         // layer-1: first col of low half
    const int r0 = gg << 3;         // layer-1: first row

    __shared__ float sxT[DIM_IN][BS];   // 3.2 KB
    __shared__ short h1b[BS][H];        // 8 KB, h1 as bf16 bits, linear
    __shared__ float w2t[2][32 * 64];   // 16 KB, half-tile double buffer

    const float* W1p = W1 + (size_t)p * (DIM_IN * H);
    const float* W2p = W2 + (size_t)p * (H * H);

    // ---- small loads first (oldest in vmcnt FIFO; retire before staging) ----
    const float4 b1l = *reinterpret_cast<const float4*>(b1 + (size_t)p * H + c0);
    const float4 b1h = *reinterpret_cast<const float4*>(b1 + (size_t)p * H + 64 + c0);
    float b2v[8], w3v[8];
    #pragma unroll
    for (int nb = 0; nb < 8; ++nb) {
        b2v[nb] = b2[(size_t)p * H + 16 * nb + cc];
        w3v[nb] = W3[(size_t)p * H + 16 * nb + cc];
    }
    const float b3s = b3[p];
    asm volatile("" ::: "memory");

    // half-tiles 0,1 (KT=0, both column halves) in flight during layer 1
    STAGE_TILE(0, 0, 0)
    STAGE_TILE(1, 0, 1)
    asm volatile("" ::: "memory");

    // stage x^T
    for (int i = t; i < DIM_IN * BS; i += 64)
        sxT[i >> 5][i & 31] = x[(i & 31) * DIM_IN + (i >> 5)];
    asm volatile("s_waitcnt lgkmcnt(0)" ::: "memory");

    // ---------------- layer 1: h1 = leaky(x @ W1 + b1), f32 VALU ----------------
    float aL1[8][8];
    {
        const float bv[8] = {b1l.x, b1l.y, b1l.z, b1l.w, b1h.x, b1h.y, b1h.z, b1h.w};
        #pragma unroll
        for (int i = 0; i < 8; ++i)
            #pragma unroll
            for (int c = 0; c < 8; ++c)
                aL1[i][c] = bv[c];
    }
    #pragma unroll 5
    for (int d = 0; d < DIM_IN; ++d) {
        const float4 a0 = *reinterpret_cast<const float4*>(&sxT[d][r0]);
        const float4 a1 = *reinterpret_cast<const float4*>(&sxT[d][r0 + 4]);
        const float av[8] = {a0.x, a0.y, a0.z, a0.w, a1.x, a1.y, a1.z, a1.w};
        const float4 wl = *reinterpret_cast<const float4*>(W1p + d * H + c0);
        const float4 wh = *reinterpret_cast<const float4*>(W1p + d * H + 64 + c0);
        const float wv[8] = {wl.x, wl.y, wl.z, wl.w, wh.x, wh.y, wh.z, wh.w};
        #pragma unroll
        for (int i = 0; i < 8; ++i)
            #pragma unroll
            for (int c = 0; c < 8; ++c)
                aL1[i][c] += av[i] * wv[c];
    }

    // write h1 (leaky, RNE bf16) into the linear [32][128] layout
    #pragma unroll
    for (int i = 0; i < 8; ++i) {
        short4v lo, hi;
        lo[0] = bf_rne(leaky(aL1[i][0])); lo[1] = bf_rne(leaky(aL1[i][1]));
        lo[2] = bf_rne(leaky(aL1[i][2])); lo[3] = bf_rne(leaky(aL1[i][3]));
        hi[0] = bf_rne(leaky(aL1[i][4])); hi[1] = bf_rne(leaky(aL1[i][5]));
        hi[2] = bf_rne(leaky(aL1[i][6])); hi[3] = bf_rne(leaky(aL1[i][7]));
        *reinterpret_cast<short4v*>(&h1b[r0 + i][4 * cc])      = lo;
        *reinterpret_cast<short4v*>(&h1b[r0 + i][64 + 4 * cc]) = hi;
    }
    asm volatile("s_waitcnt lgkmcnt(0)" ::: "memory");
    __builtin_amdgcn_sched_barrier(0);

    // ---------------- layer 2: h2 = leaky(h1 @ W2 + b2), bf16 MFMA ----------------
    f32x4 ac0[8], ac1[8];
    #pragma unroll
    for (int nb = 0; nb < 8; ++nb) {
        ac0[nb] = (f32x4){0.f, 0.f, 0.f, 0.f};
        ac1[nb] = (f32x4){0.f, 0.f, 0.f, 0.f};
    }

    // 8 half-tiles (KT=0..3 x HF=0,1); steady state keeps 16 insts (2 tiles)
    // outstanding; vmcnt(8) = oldest tile fully landed.
    #pragma unroll 1
    for (int kt = 0; kt < 3; ++kt) {
        asm volatile("s_waitcnt vmcnt(8)" ::: "memory");
        CONSUME_TILE(0, kt, 0)
        asm volatile("s_waitcnt lgkmcnt(0)" ::: "memory");
        STAGE_TILE(0, kt + 1, 0)
        asm volatile("s_waitcnt vmcnt(8)" ::: "memory");
        CONSUME_TILE(1, kt, 1)
        asm volatile("s_waitcnt lgkmcnt(0)" ::: "memory");
        STAGE_TILE(1, kt + 1, 1)
    }
    asm volatile("s_waitcnt vmcnt(8)" ::: "memory");
    CONSUME_TILE(0, 3, 0)
    asm volatile("s_waitcnt vmcnt(0)" ::: "memory");
    CONSUME_TILE(1, 3, 1)

    // ---------------- layer 3: y = leaky(h2 + b2) @ W3 + b3 ----------------
    // lane holds D rows b = {4*gg+q, 16+4*gg+q}, col n = 16*nb + cc
    float s0[4], s1[4];
    #pragma unroll
    for (int q = 0; q < 4; ++q) {
        float a = 0.f, b = 0.f;
        #pragma unroll
        for (int nb = 0; nb < 8; ++nb) {
            a += leaky(ac0[nb][q] + b2v[nb]) * w3v[nb];
            b += leaky(ac1[nb][q] + b2v[nb]) * w3v[nb];
        }
        s0[q] = a; s1[q] = b;
    }
    // reduce across the 16 cc lanes
    #pragma unroll
    for (int m = 8; m >= 1; m >>= 1) {
        #pragma unroll
        for (int q = 0; q < 4; ++q) {
            s0[q] += __shfl_xor(s0[q], m);
            s1[q] += __shfl_xor(s1[q], m);
        }
    }
    if (cc == 0) {
        #pragma unroll
        for (int q = 0; q < 4; ++q) {
            y[(size_t)(4 * gg + q) * P + p]      = s0[q] + b3s;
            y[(size_t)(16 + 4 * gg + q) * P + p] = s1[q] + b3s;
        }
    }
}

extern "C" void kernel_launch(void* const* d_in, const int* in_sizes, int n_in,
                              void* d_out, int out_size, void* d_ws, size_t ws_size,
                              hipStream_t stream) {
    const float* x  = (const float*)d_in[0];
    const float* W1 = (const float*)d_in[1];
    const float* b1 = (const float*)d_in[2];
    const float* W2 = (const float*)d_in[3];
    const float* b2 = (const float*)d_in[4];
    const float* W3 = (const float*)d_in[5];
    const float* b3 = (const float*)d_in[6];
    float* y = (float*)d_out;

    pixel_mlp_kernel<<<dim3(P), dim3(64), 0, stream>>>(x, W1, b1, W2, b2, W3, b3, y);
}

// Round 13
// 130.366 us; speedup vs baseline: 4.6314x; 1.0535x over previous
//
#include <hip/hip_runtime.h>

// PerceptronSP: 8000 independent per-pixel MLPs sharing input x.
//   h1 = leaky(x @ W1[p] + b1[p])   [32x25]@[25x128]   f32 VALU
//   h2 = leaky(h1 @ W2[p] + b2[p])  [32x128]@[128x128] bf16 MFMA
//   y[:,p] = h2 @ W3[p] + b3[p]
// ~650 MB streamed once -> ~100 us floor @ 6.6 TB/s.
//
// R13: occupancy 5 -> 8 blocks/CU (2 waves/SIMD). W2 tiles shrink to 4 KB
// [32k x 32n] column-quarters; LDS 19.2 KB. 16 tiles/pixel, same verified
// counted-vmcnt double buffer as R12 (vmcnt(4) = oldest tile landed, 2 tiles
// in flight, drain only at tail). Acc index 2*QT+nb with QT literal.

constexpr int DIM_IN = 25;
constexpr int H      = 128;
constexpr int P      = 8000;
constexpr int BS     = 32;
constexpr float NEG  = 0.01f;

typedef short  short4v __attribute__((ext_vector_type(4)));
typedef short  short8v __attribute__((ext_vector_type(8)));
typedef float  f32x4   __attribute__((ext_vector_type(4)));

__device__ __forceinline__ float leaky(float v) { return v >= 0.f ? v : NEG * v; }

__device__ __forceinline__ short bf_rne(float f) {   // f32 -> bf16 bits, RNE
    unsigned u = __builtin_bit_cast(unsigned, f);
    return (short)((u + 0x7fffu + ((u >> 16) & 1u)) >> 16);
}
__device__ __forceinline__ short bf_rna(float f) {   // f32 -> bf16 bits, round-nearest-away
    unsigned u = __builtin_bit_cast(unsigned, f);
    return (short)((u + 0x8000u) >> 16);
}

// stage one 4KB quarter-tile: W2 rows [32*KT,+32) x cols [32*QT,+32).
// 4 x 1KB DMA insts; inst i covers rows 8i..8i+7 (8 x 128B segments).
// lane l -> row (l>>3), col-quad (l&7); LDS dst wave-uniform + lane*16B
// -> buf is [32][32] f32 row-major.
#define STAGE_Q(BUF, KT, QT) {                                                 \
    const float* gsrc_ = W2p + (size_t)(32 * (KT) + (t >> 3)) * H              \
                         + 32 * (QT) + ((t & 7) << 2);                         \
    float* dst_ = &w2t[BUF][0];                                                \
    _Pragma("unroll")                                                          \
    for (int i_ = 0; i_ < 4; ++i_)                                             \
        __builtin_amdgcn_global_load_lds(                                      \
            (const __attribute__((address_space(1))) unsigned*)(gsrc_ + (size_t)i_ * 8 * H), \
            (__attribute__((address_space(3))) unsigned*)(dst_ + i_ * 256),    \
            16, 0, 0); }

// consume one quarter-tile with K=32 MFMA (R8/R12-verified mapping: lane gg
// owns k = 8*gg + j for BOTH A and B -> any hw K-permutation cancels).
// A-frag: h1b[row=cc][k=32*KT+8*gg+j], one b128 read (+ row 16+cc).
// B-frag: buf[k=8*gg+j][n=16*nb+cc], 8 strided b32 reads + bf16 round.
// QT must be a LITERAL so accumulator indices are compile-time.
#define CONSUME_Q(BUF, KT, QT) {                                               \
    const short8v a0_ = *reinterpret_cast<const short8v*>(                     \
        &h1b[cc][32 * (KT) + 8 * gg]);                                         \
    const short8v a1_ = *reinterpret_cast<const short8v*>(                     \
        &h1b[16 + cc][32 * (KT) + 8 * gg]);                                    \
    const float* tb_ = &w2t[BUF][8 * gg * 32 + cc];                            \
    _Pragma("unroll")                                                          \
    for (int nb_ = 0; nb_ < 2; ++nb_) {                                        \
        const float* col_ = tb_ + 16 * nb_;                                    \
        short8v bf_;                                                           \
        bf_[0] = bf_rna(col_[0 * 32]); bf_[1] = bf_rna(col_[1 * 32]);          \
        bf_[2] = bf_rna(col_[2 * 32]); bf_[3] = bf_rna(col_[3 * 32]);          \
        bf_[4] = bf_rna(col_[4 * 32]); bf_[5] = bf_rna(col_[5 * 32]);          \
        bf_[6] = bf_rna(col_[6 * 32]); bf_[7] = bf_rna(col_[7 * 32]);          \
        ac0[2 * (QT) + nb_] = __builtin_amdgcn_mfma_f32_16x16x32_bf16(         \
            a0_, bf_, ac0[2 * (QT) + nb_], 0, 0, 0);                           \
        ac1[2 * (QT) + nb_] = __builtin_amdgcn_mfma_f32_16x16x32_bf16(         \
            a1_, bf_, ac1[2 * (QT) + nb_], 0, 0, 0);                           \
    } }

// one pipeline step: tile u = 4*kt+qt; buf = qt&1; restage same buf with u+2.
#define QSTEP(KT, QT, NKT, NQT) {                                              \
    asm volatile("s_waitcnt vmcnt(4)" ::: "memory");                           \
    CONSUME_Q((QT) & 1, KT, QT)                                                \
    asm volatile("s_waitcnt lgkmcnt(0)" ::: "memory");                         \
    STAGE_Q((QT) & 1, NKT, NQT) }

__global__ __launch_bounds__(64, 2) void pixel_mlp_kernel(
    const float* __restrict__ x,    // [BS][DIM_IN]
    const float* __restrict__ W1,   // [P][DIM_IN][H]
    const float* __restrict__ b1,   // [P][H]
    const float* __restrict__ W2,   // [P][H][H]
    const float* __restrict__ b2,   // [P][H]
    const float* __restrict__ W3,   // [P][H]
    const float* __restrict__ b3,   // [P]
    float* __restrict__ y)          // [BS][P]
{
    const int p  = blockIdx.x;
    const int t  = threadIdx.x;     // 0..63, one wave
    const int cc = t & 15;          // MFMA n-lane / layer-1 col group
    const int gg = t >> 4;          // MFMA k-group / layer-1 row group
    const int c0 = cc << 2;         // layer-1: first col of low half
    const int r0 = gg << 3;         // layer-1: first row

    __shared__ float sxT[DIM_IN][BS];   // 3.2 KB
    __shared__ short h1b[BS][H];        // 8 KB, h1 as bf16 bits, linear
    __shared__ float w2t[2][32 * 32];   // 8 KB, quarter-tile double buffer

    const float* W1p = W1 + (size_t)p * (DIM_IN * H);
    const float* W2p = W2 + (size_t)p * (H * H);

    // ---- small loads first (oldest in vmcnt FIFO; retire before staging) ----
    const float4 b1l = *reinterpret_cast<const float4*>(b1 + (size_t)p * H + c0);
    const float4 b1h = *reinterpret_cast<const float4*>(b1 + (size_t)p * H + 64 + c0);
    float b2v[8], w3v[8];
    #pragma unroll
    for (int nb = 0; nb < 8; ++nb) {
        b2v[nb] = b2[(size_t)p * H + 16 * nb + cc];
        w3v[nb] = W3[(size_t)p * H + 16 * nb + cc];
    }
    const float b3s = b3[p];
    asm volatile("" ::: "memory");

    // tiles (0,0),(0,1) in flight during layer 1
    STAGE_Q(0, 0, 0)
    STAGE_Q(1, 0, 1)
    asm volatile("" ::: "memory");

    // stage x^T
    for (int i = t; i < DIM_IN * BS; i += 64)
        sxT[i >> 5][i & 31] = x[(i & 31) * DIM_IN + (i >> 5)];
    asm volatile("s_waitcnt lgkmcnt(0)" ::: "memory");

    // ---------------- layer 1: h1 = leaky(x @ W1 + b1), f32 VALU ----------------
    float aL1[8][8];
    {
        const float bv[8] = {b1l.x, b1l.y, b1l.z, b1l.w, b1h.x, b1h.y, b1h.z, b1h.w};
        #pragma unroll
        for (int i = 0; i < 8; ++i)
            #pragma unroll
            for (int c = 0; c < 8; ++c)
                aL1[i][c] = bv[c];
    }
    #pragma unroll 5
    for (int d = 0; d < DIM_IN; ++d) {
        const float4 a0 = *reinterpret_cast<const float4*>(&sxT[d][r0]);
        const float4 a1 = *reinterpret_cast<const float4*>(&sxT[d][r0 + 4]);
        const float av[8] = {a0.x, a0.y, a0.z, a0.w, a1.x, a1.y, a1.z, a1.w};
        const float4 wl = *reinterpret_cast<const float4*>(W1p + d * H + c0);
        const float4 wh = *reinterpret_cast<const float4*>(W1p + d * H + 64 + c0);
        const float wv[8] = {wl.x, wl.y, wl.z, wl.w, wh.x, wh.y, wh.z, wh.w};
        #pragma unroll
        for (int i = 0; i < 8; ++i)
            #pragma unroll
            for (int c = 0; c < 8; ++c)
                aL1[i][c] += av[i] * wv[c];
    }

    // write h1 (leaky, RNE bf16) into the linear [32][128] layout
    #pragma unroll
    for (int i = 0; i < 8; ++i) {
        short4v lo, hi;
        lo[0] = bf_rne(leaky(aL1[i][0])); lo[1] = bf_rne(leaky(aL1[i][1]));
        lo[2] = bf_rne(leaky(aL1[i][2])); lo[3] = bf_rne(leaky(aL1[i][3]));
        hi[0] = bf_rne(leaky(aL1[i][4])); hi[1] = bf_rne(leaky(aL1[i][5]));
        hi[2] = bf_rne(leaky(aL1[i][6])); hi[3] = bf_rne(leaky(aL1[i][7]));
        *reinterpret_cast<short4v*>(&h1b[r0 + i][4 * cc])      = lo;
        *reinterpret_cast<short4v*>(&h1b[r0 + i][64 + 4 * cc]) = hi;
    }
    asm volatile("s_waitcnt lgkmcnt(0)" ::: "memory");
    __builtin_amdgcn_sched_barrier(0);

    // ---------------- layer 2: h2 = leaky(h1 @ W2 + b2), bf16 MFMA ----------------
    f32x4 ac0[8], ac1[8];
    #pragma unroll
    for (int nb = 0; nb < 8; ++nb) {
        ac0[nb] = (f32x4){0.f, 0.f, 0.f, 0.f};
        ac1[nb] = (f32x4){0.f, 0.f, 0.f, 0.f};
    }

    // 16 quarter-tiles (kt 0..3 x qt 0..3); 2 tiles (8 insts) in flight;
    // vmcnt(4) = oldest tile fully landed. Restage stops at tile 15.
    #pragma unroll 1
    for (int kt = 0; kt < 3; ++kt) {
        QSTEP(kt, 0, kt, 2)
        QSTEP(kt, 1, kt, 3)
        QSTEP(kt, 2, kt + 1, 0)
        QSTEP(kt, 3, kt + 1, 1)
    }
    QSTEP(3, 0, 3, 2)
    QSTEP(3, 1, 3, 3)
    asm volatile("s_waitcnt vmcnt(4)" ::: "memory");
    CONSUME_Q(0, 3, 2)
    asm volatile("s_waitcnt vmcnt(0)" ::: "memory");
    CONSUME_Q(1, 3, 3)

    // ---------------- layer 3: y = leaky(h2 + b2) @ W3 + b3 ----------------
    // lane holds D rows b = {4*gg+q, 16+4*gg+q}, col n = 16*nb + cc
    float s0[4], s1[4];
    #pragma unroll
    for (int q = 0; q < 4; ++q) {
        float a = 0.f, b = 0.f;
        #pragma unroll
        for (int nb = 0; nb < 8; ++nb) {
            a += leaky(ac0[nb][q] + b2v[nb]) * w3v[nb];
            b += leaky(ac1[nb][q] + b2v[nb]) * w3v[nb];
        }
        s0[q] = a; s1[q] = b;
    }
    // reduce across the 16 cc lanes
    #pragma unroll
    for (int m = 8; m >= 1; m >>= 1) {
        #pragma unroll
        for (int q = 0; q < 4; ++q) {
            s0[q] += __shfl_xor(s0[q], m);
            s1[q] += __shfl_xor(s1[q], m);
        }
    }
    if (cc == 0) {
        #pragma unroll
        for (int q = 0; q < 4; ++q) {
            y[(size_t)(4 * gg + q) * P + p]      = s0[q] + b3s;
            y[(size_t)(16 + 4 * gg + q) * P + p] = s1[q] + b3s;
        }
    }
}

extern "C" void kernel_launch(void* const* d_in, const int* in_sizes, int n_in,
                              void* d_out, int out_size, void* d_ws, size_t ws_size,
                              hipStream_t stream) {
    const float* x  = (const float*)d_in[0];
    const float* W1 = (const float*)d_in[1];
    const float* b1 = (const float*)d_in[2];
    const float* W2 = (const float*)d_in[3];
    const float* b2 = (const float*)d_in[4];
    const float* W3 = (const float*)d_in[5];
    const float* b3 = (const float*)d_in[6];
    float* y = (float*)d_out;

    pixel_mlp_kernel<<<dim3(P), dim3(64), 0, stream>>>(x, W1, b1, W2, b2, W3, b3, y);
}